// Round 1
// baseline (277.061 us; speedup 1.0000x reference)
//
#include <hip/hip_runtime.h>

// Problem constants (fixed by setup_inputs).
namespace {
constexpr int kB = 8;
constexpr int kC = 16;
constexpr int kH = 512;
constexpr int kW = 512;
constexpr int kNPB = kC * kH * kW;                  // 4,194,304 pixels per batch
constexpr int kMaxPeaks = 262144;
constexpr int kTPB = 256;
constexpr int kPixPerThread = 4;
constexpr int kPixPerBlock = kTPB * kPixPerThread;  // 1024 = exactly 2 rows of one channel
constexpr int kNBlkPerBatch = kNPB / kPixPerBlock;  // 4096
constexpr long long kPeaksElems = (long long)kB * kMaxPeaks * 3;  // 6,291,456
}

// Compute peak flags + values for 4 consecutive pixels (y, x0..x0+3) of one
// 512x512 channel image. Out-of-image neighbors are -inf (matches the
// reference's reduce_window -inf padding).
__device__ __forceinline__ void peak_flags4(const float* __restrict__ img,
                                            int y, int x0,
                                            float v[4], int f[4]) {
  const float NEG = -3.402823466e38f;  // inputs are finite normals; -FLT_MAX is safe
  float row[3][6];
#pragma unroll
  for (int r = 0; r < 3; ++r) {
    int yy = y + r - 1;
    if (yy >= 0 && yy < kH) {
      const float* p = img + yy * kW + x0;
      float4 c4 = *reinterpret_cast<const float4*>(p);  // x0 % 4 == 0 -> 16B aligned
      row[r][1] = c4.x; row[r][2] = c4.y; row[r][3] = c4.z; row[r][4] = c4.w;
      row[r][0] = (x0 > 0) ? p[-1] : NEG;
      row[r][5] = (x0 + 4 < kW) ? p[4] : NEG;
    } else {
#pragma unroll
      for (int i = 0; i < 6; ++i) row[r][i] = NEG;
    }
  }
#pragma unroll
  for (int i = 0; i < 4; ++i) {
    v[i] = row[1][i + 1];
    float m = row[0][i];
    m = fmaxf(m, row[0][i + 1]); m = fmaxf(m, row[0][i + 2]);
    m = fmaxf(m, row[1][i]);     m = fmaxf(m, row[1][i + 1]); m = fmaxf(m, row[1][i + 2]);
    m = fmaxf(m, row[2][i]);     m = fmaxf(m, row[2][i + 1]); m = fmaxf(m, row[2][i + 2]);
    f[i] = ((v[i] == m) && (v[i] > 0.0f)) ? 1 : 0;
  }
}

// Decode a block's position: block covers 1024 consecutive flat pixels of one batch.
__device__ __forceinline__ void decode(int blk, int t, int& b, int& local,
                                       int& c, int& y, int& x0) {
  b = blk / kNBlkPerBatch;
  int cblk = blk - b * kNBlkPerBatch;
  local = cblk * kPixPerBlock + t * kPixPerThread;  // flat index within batch
  c = local >> 18;            // / (512*512)
  y = (local >> 9) & (kH - 1);
  x0 = local & (kW - 1);      // multiple of 4
}

__global__ void __launch_bounds__(kTPB)
peak_count_kernel(const float* __restrict__ hm, int* __restrict__ blk_cnt) {
  int t = threadIdx.x;
  int b, local, c, y, x0;
  decode(blockIdx.x, t, b, local, c, y, x0);
  const float* img = hm + (long long)b * kNPB + (long long)c * (kH * kW);

  float v[4]; int f[4];
  peak_flags4(img, y, x0, v, f);
  int cnt = f[0] + f[1] + f[2] + f[3];

  // wave reduce (64-wide), then cross-wave via LDS
  int lane = t & 63, wv = t >> 6;
#pragma unroll
  for (int d = 32; d >= 1; d >>= 1) cnt += __shfl_down(cnt, d, 64);
  __shared__ int wsum[kTPB / 64];
  if (lane == 0) wsum[wv] = cnt;
  __syncthreads();
  if (t == 0) {
    int s = 0;
#pragma unroll
    for (int i = 0; i < kTPB / 64; ++i) s += wsum[i];
    blk_cnt[blockIdx.x] = s;
  }
}

// One block per batch: exclusive prefix sum over 4096 block counts.
// Writes per-block offsets and the batch total (as float32 — harness reads the
// whole out buffer as the first output's dtype).
__global__ void __launch_bounds__(256)
scan_kernel(const int* __restrict__ blk_cnt, int* __restrict__ blk_off,
            float* __restrict__ counts_out) {
  int b = blockIdx.x;
  const int* cnt = blk_cnt + b * kNBlkPerBatch;
  int* off = blk_off + b * kNBlkPerBatch;
  int t = threadIdx.x;
  constexpr int kPer = kNBlkPerBatch / 256;  // 16
  int base = t * kPer;

  int vals[kPer];
  int s = 0;
#pragma unroll
  for (int k = 0; k < kPer; ++k) { vals[k] = cnt[base + k]; s += vals[k]; }

  int lane = t & 63, wv = t >> 6;
  int incl = s;
#pragma unroll
  for (int d = 1; d < 64; d <<= 1) {
    int u = __shfl_up(incl, d, 64);
    if (lane >= d) incl += u;
  }
  __shared__ int wsum[4];
  if (lane == 63) wsum[wv] = incl;
  __syncthreads();
  int wbase = 0;
  for (int i = 0; i < wv; ++i) wbase += wsum[i];

  int run = wbase + incl - s;  // exclusive offset for this thread's chunk
#pragma unroll
  for (int k = 0; k < kPer; ++k) { off[base + k] = run; run += vals[k]; }

  if (t == 255) counts_out[b] = (float)run;  // run == batch total here
}

__global__ void __launch_bounds__(kTPB)
peak_write_kernel(const float* __restrict__ hm, const int* __restrict__ blk_off,
                  float* __restrict__ peaks) {
  int t = threadIdx.x;
  int b, local, c, y, x0;
  decode(blockIdx.x, t, b, local, c, y, x0);
  const float* img = hm + (long long)b * kNPB + (long long)c * (kH * kW);

  float v[4]; int f[4];
  peak_flags4(img, y, x0, v, f);
  int cnt = f[0] + f[1] + f[2] + f[3];

  // block exclusive scan (threads ascending == flat index ascending)
  int lane = t & 63, wv = t >> 6;
  int incl = cnt;
#pragma unroll
  for (int d = 1; d < 64; d <<= 1) {
    int u = __shfl_up(incl, d, 64);
    if (lane >= d) incl += u;
  }
  __shared__ int wsum[kTPB / 64];
  if (lane == 63) wsum[wv] = incl;
  __syncthreads();
  int wbase = 0;
  for (int i = 0; i < wv; ++i) wbase += wsum[i];

  int rank = blk_off[blockIdx.x] + wbase + incl - cnt;
#pragma unroll
  for (int i = 0; i < 4; ++i) {
    if (f[i] && rank < kMaxPeaks) {
      float* o = peaks + ((long long)b * kMaxPeaks + rank) * 3;
      o[0] = (float)(x0 + i);
      o[1] = (float)y;
      o[2] = v[i];
    }
    rank += f[i];
  }
}

extern "C" void kernel_launch(void* const* d_in, const int* in_sizes, int n_in,
                              void* d_out, int out_size, void* d_ws, size_t ws_size,
                              hipStream_t stream) {
  const float* hm = (const float*)d_in[0];
  float* out = (float*)d_out;
  float* counts_out = out + kPeaksElems;

  int* blk_cnt = (int*)d_ws;                    // B*4096 ints
  int* blk_off = blk_cnt + kB * kNBlkPerBatch;  // B*4096 ints

  // Zero-fill output (zero-padding semantics for rows beyond counts[b]).
  hipMemsetAsync(d_out, 0, (size_t)out_size * sizeof(float), stream);

  peak_count_kernel<<<kB * kNBlkPerBatch, kTPB, 0, stream>>>(hm, blk_cnt);
  scan_kernel<<<kB, 256, 0, stream>>>(blk_cnt, blk_off, counts_out);
  peak_write_kernel<<<kB * kNBlkPerBatch, kTPB, 0, stream>>>(hm, blk_off, out);
}